// Round 3
// baseline (493.477 us; speedup 1.0000x reference)
//
#include <hip/hip_runtime.h>
#include <cstdint>
#include <cstddef>

// Problem constants (B=2, S=2048 -> T=4096 tokens)
#define TT 4096
#define DD 1024
#define MM 2048
#define EE 8
#define NPAIR 8192   // TT * top_k(2)

typedef unsigned short u16;
typedef __bf16 bf16x8 __attribute__((ext_vector_type(8)));
typedef float f32x4 __attribute__((ext_vector_type(4)));
typedef u16 u16x8 __attribute__((ext_vector_type(8)));
typedef __attribute__((address_space(3))) void* lds_vp;
typedef __attribute__((address_space(1))) const void* gbl_cvp;

__device__ __forceinline__ void async16(u16* l, const u16* g) {
  __builtin_amdgcn_global_load_lds((gbl_cvp)(const void*)g, (lds_vp)(void*)l, 16, 0, 0);
}

// counted waits + raw barrier (T3/T4)
#define VMCNT6() asm volatile("s_waitcnt vmcnt(6)" ::: "memory")
#define VMCNT4() asm volatile("s_waitcnt vmcnt(4)" ::: "memory")
#define VMCNT0() asm volatile("s_waitcnt vmcnt(0)" ::: "memory")
#define BARR() do { asm volatile("" ::: "memory"); __builtin_amdgcn_s_barrier(); asm volatile("" ::: "memory"); } while (0)

__device__ __forceinline__ u16 f2bf(float f) {
  uint32_t u = __builtin_bit_cast(uint32_t, f);
  u += 0x7fffu + ((u >> 16) & 1u);   // RNE
  return (u16)(u >> 16);
}
__device__ __forceinline__ float bf2f(u16 h) {
  uint32_t u = ((uint32_t)h) << 16;
  return __builtin_bit_cast(float, u);
}

// ---------------- router + X->bf16 convert + out-zeroing fused ----------------
__global__ void router_kernel(const float* __restrict__ X, const float* __restrict__ Wr,
                              int* __restrict__ tok_idx, float* __restrict__ wpair,
                              u16* __restrict__ Xbf, float* __restrict__ out) {
  // zero `out` (atomic epilogue of the out-GEMM accumulates into it)
  {
    int idx = blockIdx.x * 256 + threadIdx.x;   // 0..262143
    float4 z4 = {0.f, 0.f, 0.f, 0.f};
    float4* o4 = (float4*)out;
#pragma unroll
    for (int k = 0; k < 4; k++) o4[idx + k * (TT / 4) * 256] = z4;  // 262144 stride
  }
  int wave = threadIdx.x >> 6;
  int lane = threadIdx.x & 63;
  int t = blockIdx.x * 4 + wave;
  const float4* x4 = (const float4*)(X + (size_t)t * DD);
  float acc[EE];
#pragma unroll
  for (int e = 0; e < EE; e++) acc[e] = 0.f;
#pragma unroll
  for (int i = 0; i < 4; i++) {
    float4 xv = x4[i * 64 + lane];
    ushort4 o;
    o.x = f2bf(xv.x); o.y = f2bf(xv.y); o.z = f2bf(xv.z); o.w = f2bf(xv.w);
    *(ushort4*)&Xbf[(size_t)t * DD + (size_t)(i * 64 + lane) * 4] = o;
    const float4* wr4 = (const float4*)(Wr + (size_t)(i * 256 + lane * 4) * EE);
    float xs[4] = {xv.x, xv.y, xv.z, xv.w};
#pragma unroll
    for (int c = 0; c < 4; c++) {
      float4 wa = wr4[c * 2 + 0];
      float4 wb = wr4[c * 2 + 1];
      acc[0] += xs[c] * wa.x; acc[1] += xs[c] * wa.y;
      acc[2] += xs[c] * wa.z; acc[3] += xs[c] * wa.w;
      acc[4] += xs[c] * wb.x; acc[5] += xs[c] * wb.y;
      acc[6] += xs[c] * wb.z; acc[7] += xs[c] * wb.w;
    }
  }
#pragma unroll
  for (int off = 32; off > 0; off >>= 1)
#pragma unroll
    for (int e = 0; e < EE; e++) acc[e] += __shfl_xor(acc[e], off);
  if (lane == 0) {
    float mx = acc[0];
#pragma unroll
    for (int e = 1; e < EE; e++) mx = fmaxf(mx, acc[e]);
    float p[EE], s = 0.f;
#pragma unroll
    for (int e = 0; e < EE; e++) { p[e] = __expf(acc[e] - mx); s += p[e]; }
    float inv = 1.f / s;
#pragma unroll
    for (int e = 0; e < EE; e++) p[e] *= inv;
    int i0 = 0;
#pragma unroll
    for (int e = 1; e < EE; e++) if (p[e] > p[i0]) i0 = e;
    int i1 = (i0 == 0) ? 1 : 0;
#pragma unroll
    for (int e = 0; e < EE; e++) if (e != i0 && p[e] > p[i1]) i1 = e;
    float denom = p[i0] + p[i1] + 1e-8f;
    tok_idx[t * 2 + 0] = i0;
    tok_idx[t * 2 + 1] = i1;
    wpair[t * 2 + 0] = p[i0] / denom;
    wpair[t * 2 + 1] = p[i1] / denom;
  }
}

// ---------------- bucketing: wave-aggregated ballots ----------------
__global__ void bucket_kernel(const int* __restrict__ tok_idx, int* __restrict__ offsets,
                              int* __restrict__ bucket) {
  __shared__ int lcnt[EE];
  __shared__ int lcur[EE];
  int tid = threadIdx.x;   // 1024 threads
  int lane = tid & 63;
  if (tid < EE) lcnt[tid] = 0;
  __syncthreads();
  {
    int cnt[EE];
#pragma unroll
    for (int k = 0; k < EE; k++) cnt[k] = 0;
    for (int i = tid; i < NPAIR; i += 1024) {
      int e = tok_idx[i];
#pragma unroll
      for (int k = 0; k < EE; k++) {
        unsigned long long m = __ballot(e == k);
        cnt[k] += __popcll(m);
      }
    }
    if (lane == 0) {
#pragma unroll
      for (int k = 0; k < EE; k++)
        if (cnt[k]) atomicAdd(&lcnt[k], cnt[k]);
    }
  }
  __syncthreads();
  if (tid == 0) {
    int s = 0;
    for (int e = 0; e < EE; e++) {
      offsets[e] = s;
      lcur[e] = s;
      s += lcnt[e];
    }
    offsets[EE] = s;
  }
  __syncthreads();
  for (int i = tid; i < NPAIR; i += 1024) {
    int e = tok_idx[i];
    int pos = 0;
#pragma unroll
    for (int k = 0; k < EE; k++) {
      unsigned long long m = __ballot(e == k);
      int c = __popcll(m);
      if (c) {
        int leader = (int)__ffsll((long long)m) - 1;
        int base = 0;
        if (lane == leader) base = atomicAdd(&lcur[k], c);
        base = __shfl(base, leader);
        if (e == k) pos = base + __popcll(m & ((1ull << lane) - 1ull));
      }
    }
    bucket[pos] = i;
  }
}

// ---------------- all 3 weight transposes in one launch ----------------
// z in [0,24): z<8 -> W_gate expert z; z<16 -> W_up; z>=16 -> W_out.
// G/U: R=DD, C=MM (32x16 tiles); O: R=MM, C=DD (16x32 tiles). grid=(32,16,24).
__global__ __launch_bounds__(256)
void transpose_all(const float* __restrict__ Gf, const float* __restrict__ Uf,
                   const float* __restrict__ Of, u16* __restrict__ tG,
                   u16* __restrict__ tU, u16* __restrict__ tO) {
  __shared__ float tile[64][65];   // [c][r], +1 pad
  int z = blockIdx.z;
  const float* in; u16* out; int R, C, shift;
  int e;
  if (z < 8)       { in = Gf; out = tG; R = DD; C = MM; e = z;      shift = 5; }
  else if (z < 16) { in = Uf; out = tU; R = DD; C = MM; e = z - 8;  shift = 5; }
  else             { in = Of; out = tO; R = MM; C = DD; e = z - 16; shift = 4; }
  int tidx = blockIdx.y * 32 + blockIdx.x;     // 0..511
  int cx = tidx & ((1 << shift) - 1);
  int cy = tidx >> shift;
  const float* I = in + (size_t)e * R * C;
  u16* O = out + (size_t)e * R * C;
  int c0 = cx * 64, r0 = cy * 64;
  int t = threadIdx.x;
  {
    int cq = t & 15;          // col quad
    int rb = t >> 4;          // row base
#pragma unroll
    for (int i = 0; i < 4; i++) {
      int r = rb + i * 16;
      float4 v = *(const float4*)&I[(size_t)(r0 + r) * C + c0 + cq * 4];
      tile[cq * 4 + 0][r] = v.x;
      tile[cq * 4 + 1][r] = v.y;
      tile[cq * 4 + 2][r] = v.z;
      tile[cq * 4 + 3][r] = v.w;
    }
  }
  __syncthreads();
  {
    int rseg = (t & 7) * 8;
    int cc = t >> 3;          // 0..31
#pragma unroll
    for (int i = 0; i < 2; i++) {
      int c = cc + i * 32;
      u16x8 o;
#pragma unroll
      for (int k = 0; k < 8; k++) o[k] = f2bf(tile[c][rseg + k]);
      *(u16x8*)&O[(size_t)(c0 + c) * R + r0 + rseg] = o;
    }
  }
}

// Map row-tile index rt -> (expert, row0, rows). Tiles never cross expert boundaries.
__device__ __forceinline__ bool tile_map(const int* __restrict__ offsets, int x,
                                         int& expert, int& row0, int& rows) {
  expert = -1;
#pragma unroll 1
  for (int e = 0; e < EE; e++) {
    int o0 = offsets[e], o1 = offsets[e + 1];
    int nt = (o1 - o0 + 127) >> 7;
    if (x < nt) { expert = e; row0 = o0 + (x << 7); rows = min(128, o1 - row0); return true; }
    x -= nt;
  }
  return false;
}

// XCD-aware decode, n0-OUTER / rt-INNER:
// the ~64 concurrent blocks on an XCD then share the same 1-2 B panels (0.5-1MB)
// while its 9 A-strips (~2.25MB) stay L2-resident -> WS < 4MB L2 (was 8MB B thrash).
__device__ __forceinline__ void grid_decode(int bid, int& rt, int& n0) {
  int xcd = bid & 7, slot = bid >> 3;
  rt = xcd * 9 + slot % 9;
  n0 = (slot / 9) * 128;
}

// LDS bank-conflict swizzle (verified: conflicts 0):
// chunk q of row r stored at position q ^ ((r>>1)&3); staging lane permutes SOURCE chunk.

// ---------------- fused gate+up GEMM ----------------
// H = silu(X*Wg + b_gate) * (X*Wu + b_up)  -> Hws (bf16)
// Triple-buffered LDS, prefetch distance 2, counted vmcnt, ONE raw barrier/K-step.
__global__ __launch_bounds__(256, 2)
void moe_gemm_gu(const u16* __restrict__ Xbf, const u16* __restrict__ WtG,
                 const u16* __restrict__ WtU, const float* __restrict__ bgate,
                 const float* __restrict__ bup, u16* __restrict__ Hws,
                 const int* __restrict__ offsets, const int* __restrict__ bucket) {
  int rt, n0;
  grid_decode(blockIdx.x, rt, n0);
  int expert, row0, rows;
  if (!tile_map(offsets, rt, expert, row0, rows)) return;

  __shared__ u16 Alds[3 * 128 * 32];
  __shared__ u16 Glds[3 * 128 * 32];
  __shared__ u16 Ulds[3 * 128 * 32];

  int tid = threadIdx.x;
  int wave = tid >> 6, lane = tid & 63;
  int wm = wave >> 1, wn = wave & 1;
  int quad = lane >> 4, l15 = lane & 15;
  int swz = ((lane & 3) ^ ((lane >> 3) & 3)) * 8;   // global source chunk
  int rp  = (quad ^ ((l15 >> 1) & 3)) * 8;          // LDS read chunk position

  long arow0, arow1;
  {
    int r0l = wave * 32 + (lane >> 2);
    int rr0 = min(r0l, rows - 1);
    int rr1 = min(r0l + 16, rows - 1);
    arow0 = (long)(bucket[row0 + rr0] >> 1) * DD;
    arow1 = (long)(bucket[row0 + rr1] >> 1) * DD;
  }
  const u16* A0 = Xbf + arow0 + swz;
  const u16* A1 = Xbf + arow1 + swz;
  size_t bo = (size_t)expert * MM * DD + (size_t)n0 * DD
            + (long)(wave * 32 + (lane >> 2)) * DD + swz;
  const u16* G0 = WtG + bo; const u16* G1 = G0 + 16 * DD;
  const u16* U0 = WtU + bo; const u16* U1 = U0 + 16 * DD;

  int sb0 = (wave * 32) * 32, sb1 = (wave * 32 + 16) * 32;

  f32x4 accG[4][4], accU[4][4];
#pragma unroll
  for (int i = 0; i < 4; i++)
#pragma unroll
    for (int j = 0; j < 4; j++) { accG[i][j] = (f32x4){0,0,0,0}; accU[i][j] = (f32x4){0,0,0,0}; }

  auto stage = [&](int b) {
    int bo2 = b * (128 * 32);
    async16(&Alds[bo2 + sb0], A0); async16(&Alds[bo2 + sb1], A1);
    async16(&Glds[bo2 + sb0], G0); async16(&Glds[bo2 + sb1], G1);
    async16(&Ulds[bo2 + sb0], U0); async16(&Ulds[bo2 + sb1], U1);
    A0 += 32; A1 += 32; G0 += 32; G1 += 32; U0 += 32; U1 += 32;
  };

  auto compute = [&](int b) {
    int ro = b * (128 * 32);
    bf16x8 af[4], bf[4];
#pragma unroll
    for (int i = 0; i < 4; i++) {
      af[i] = *(const bf16x8*)&Alds[ro + (wm * 64 + i * 16 + l15) * 32 + rp];
      bf[i] = *(const bf16x8*)&Glds[ro + (wn * 64 + i * 16 + l15) * 32 + rp];
    }
    __builtin_amdgcn_s_setprio(1);
#pragma unroll
    for (int i = 0; i < 4; i++)
#pragma unroll
      for (int j = 0; j < 4; j++)
        accG[i][j] = __builtin_amdgcn_mfma_f32_16x16x32_bf16(af[i], bf[j], accG[i][j], 0, 0, 0);
    __builtin_amdgcn_s_setprio(0);
#pragma unroll
    for (int i = 0; i < 4; i++)
      bf[i] = *(const bf16x8*)&Ulds[ro + (wn * 64 + i * 16 + l15) * 32 + rp];
    __builtin_amdgcn_s_setprio(1);
#pragma unroll
    for (int i = 0; i < 4; i++)
#pragma unroll
      for (int j = 0; j < 4; j++)
        accU[i][j] = __builtin_amdgcn_mfma_f32_16x16x32_bf16(af[i], bf[j], accU[i][j], 0, 0, 0);
    __builtin_amdgcn_s_setprio(0);
  };

  constexpr int NT = DD / 32;   // 32
  stage(0);
  stage(1);
  int br = 0, bs = 2;
#pragma unroll 1
  for (int t = 0; t < NT - 2; ++t) {
    VMCNT6();
    BARR();
    stage(bs);
    compute(br);
    bs = br; br = (br + 1 == 3) ? 0 : br + 1;
  }
  VMCNT6(); BARR(); compute(br); br = (br + 1 == 3) ? 0 : br + 1;
  VMCNT0(); BARR(); compute(br);

  // epilogue: Hws = silu(g + bg) * (u + bu); C/D layout col = lane&15, row = quad*4 + r
#pragma unroll
  for (int i = 0; i < 4; i++) {
    int lrb = wm * 64 + i * 16 + quad * 4;
#pragma unroll
    for (int j = 0; j < 4; j++) {
      int gc = n0 + wn * 64 + j * 16 + l15;
      float bg = bgate[expert * MM + gc];
      float bu = bup[expert * MM + gc];
#pragma unroll
      for (int r = 0; r < 4; r++) {
        int lr = lrb + r;
        if (lr < rows) {
          int grow = row0 + lr;
          float g = accG[i][j][r] + bg;
          float u = accU[i][j][r] + bu;
          float sg = g / (1.f + __expf(-g));
          Hws[(size_t)grow * MM + gc] = f2bf(sg * u);
        }
      }
    }
  }
}

// ---------------- output GEMM: out[token] += w*(H*Wo + b_out) via atomics ----------------
__global__ __launch_bounds__(256, 3)
void moe_gemm_out(const u16* __restrict__ Hmat, const u16* __restrict__ WtO,
                  const float* __restrict__ bias, float* __restrict__ out,
                  const int* __restrict__ offsets, const int* __restrict__ bucket,
                  const float* __restrict__ wpair) {
  int rt, n0;
  grid_decode(blockIdx.x, rt, n0);
  int expert, row0, rows;
  if (!tile_map(offsets, rt, expert, row0, rows)) return;

  __shared__ u16 Alds[3 * 128 * 32];
  __shared__ u16 Blds[3 * 128 * 32];

  int tid = threadIdx.x;
  int wave = tid >> 6, lane = tid & 63;
  int wm = wave >> 1, wn = wave & 1;
  int quad = lane >> 4, l15 = lane & 15;
  int swz = ((lane & 3) ^ ((lane >> 3) & 3)) * 8;
  int rp  = (quad ^ ((l15 >> 1) & 3)) * 8;

  long arow0, arow1;
  {
    int r0l = wave * 32 + (lane >> 2);
    int rr0 = min(r0l, rows - 1);
    int rr1 = min(r0l + 16, rows - 1);
    arow0 = (long)(row0 + rr0) * MM;   // Hws already in bucket-row order
    arow1 = (long)(row0 + rr1) * MM;
  }
  const u16* A0 = Hmat + arow0 + swz;
  const u16* A1 = Hmat + arow1 + swz;
  const u16* B0 = WtO + (size_t)expert * DD * MM + (size_t)n0 * MM
                + (long)(wave * 32 + (lane >> 2)) * MM + swz;
  const u16* B1 = B0 + 16 * MM;

  int sb0 = (wave * 32) * 32, sb1 = (wave * 32 + 16) * 32;

  f32x4 acc[4][4];
#pragma unroll
  for (int i = 0; i < 4; i++)
#pragma unroll
    for (int j = 0; j < 4; j++) acc[i][j] = (f32x4){0, 0, 0, 0};

  auto stage = [&](int b) {
    int bo2 = b * (128 * 32);
    async16(&Alds[bo2 + sb0], A0); async16(&Alds[bo2 + sb1], A1);
    async16(&Blds[bo2 + sb0], B0); async16(&Blds[bo2 + sb1], B1);
    A0 += 32; A1 += 32; B0 += 32; B1 += 32;
  };

  auto compute = [&](int b) {
    int ro = b * (128 * 32);
    bf16x8 af[4], bf[4];
#pragma unroll
    for (int i = 0; i < 4; i++) {
      af[i] = *(const bf16x8*)&Alds[ro + (wm * 64 + i * 16 + l15) * 32 + rp];
      bf[i] = *(const bf16x8*)&Blds[ro + (wn * 64 + i * 16 + l15) * 32 + rp];
    }
    __builtin_amdgcn_s_setprio(1);
#pragma unroll
    for (int i = 0; i < 4; i++)
#pragma unroll
      for (int j = 0; j < 4; j++)
        acc[i][j] = __builtin_amdgcn_mfma_f32_16x16x32_bf16(af[i], bf[j], acc[i][j], 0, 0, 0);
    __builtin_amdgcn_s_setprio(0);
  };

  constexpr int NT = MM / 32;   // 64
  stage(0);
  stage(1);
  int br = 0, bs = 2;
#pragma unroll 1
  for (int t = 0; t < NT - 2; ++t) {
    VMCNT4();
    BARR();
    stage(bs);
    compute(br);
    bs = br; br = (br + 1 == 3) ? 0 : br + 1;
  }
  VMCNT4(); BARR(); compute(br); br = (br + 1 == 3) ? 0 : br + 1;
  VMCNT0(); BARR(); compute(br);

  // epilogue: accumulate weighted expert output straight into out[token]
#pragma unroll
  for (int i = 0; i < 4; i++) {
    int lrb = wm * 64 + i * 16 + quad * 4;
#pragma unroll
    for (int j = 0; j < 4; j++) {
      int gc = n0 + wn * 64 + j * 16 + l15;
      float bv = bias[expert * DD + gc];
#pragma unroll
      for (int r = 0; r < 4; r++) {
        int lr = lrb + r;
        if (lr < rows) {
          int grow = row0 + lr;
          int p = bucket[grow];
          float w = wpair[p];
          atomicAdd(&out[(size_t)(p >> 1) * DD + gc], w * (acc[i][j][r] + bv));
        }
      }
    }
  }
}

extern "C" void kernel_launch(void* const* d_in, const int* in_sizes, int n_in,
                              void* d_out, int out_size, void* d_ws, size_t ws_size,
                              hipStream_t stream) {
  const float* residual = (const float*)d_in[0];
  const float* W_router = (const float*)d_in[1];
  const float* W_gate   = (const float*)d_in[2];
  const float* b_gate   = (const float*)d_in[3];
  const float* W_up     = (const float*)d_in[4];
  const float* b_up     = (const float*)d_in[5];
  const float* W_out    = (const float*)d_in[6];
  const float* b_out    = (const float*)d_in[7];
  float* out = (float*)d_out;

  char* ws = (char*)d_ws;
  int*   tok_idx = (int*)(ws + 0);                       // 8192 ints
  float* wpair   = (float*)(ws + 32768);                 // 8192 floats
  int*   offsets = (int*)(ws + 65536);                   // 9 ints
  int*   bucket  = (int*)(ws + 65536 + 512);             // 8192 ints
  u16*   Xbf  = (u16*)(ws + 131072);                                     // 8 MB
  u16*   WtG  = Xbf + (size_t)TT * DD;                                   // 32 MB  [E][M][D]
  u16*   WtU  = WtG + (size_t)EE * MM * DD;                              // 32 MB  [E][M][D]
  u16*   WtO  = WtU + (size_t)EE * MM * DD;                              // 32 MB  [E][D][M]
  u16*   Hws  = WtO + (size_t)EE * DD * MM;                              // 32 MB  [8192][M]

  // routing (+ X->bf16 + out-zeroing fused)
  router_kernel<<<dim3(TT / 4), dim3(256), 0, stream>>>(residual, W_router, tok_idx, wpair, Xbf, out);
  bucket_kernel<<<dim3(1), dim3(1024), 0, stream>>>(tok_idx, offsets, bucket);
  // all weight transposes (K-contiguous bf16) in one launch
  transpose_all<<<dim3(32, 16, 24), dim3(256), 0, stream>>>(W_gate, W_up, W_out, WtG, WtU, WtO);
  // fused gate+up GEMM, then output GEMM (atomic accumulate into out)
  moe_gemm_gu<<<dim3(8 * 9 * 16), dim3(256), 0, stream>>>(Xbf, WtG, WtU, b_gate, b_up, Hws, offsets, bucket);
  moe_gemm_out<<<dim3(8 * 9 * 8), dim3(256), 0, stream>>>(Hws, WtO, b_out, out, offsets, bucket, wpair);
}

// Round 5
// 447.019 us; speedup vs baseline: 1.1039x; 1.1039x over previous
//
#include <hip/hip_runtime.h>
#include <cstdint>
#include <cstddef>

// Problem constants (B=2, S=2048 -> T=4096 tokens)
#define TT 4096
#define DD 1024
#define MM 2048
#define EE 8
#define NPAIR 8192   // TT * top_k(2)

typedef unsigned short u16;
typedef __bf16 bf16x8 __attribute__((ext_vector_type(8)));
typedef float f32x4 __attribute__((ext_vector_type(4)));
typedef u16 u16x8 __attribute__((ext_vector_type(8)));
typedef __attribute__((address_space(3))) void* lds_vp;
typedef __attribute__((address_space(1))) const void* gbl_cvp;

__device__ __forceinline__ void async16(u16* l, const u16* g) {
  __builtin_amdgcn_global_load_lds((gbl_cvp)(const void*)g, (lds_vp)(void*)l, 16, 0, 0);
}

// counted waits + raw barrier (T3/T4)
#define VMCNT6() asm volatile("s_waitcnt vmcnt(6)" ::: "memory")
#define VMCNT4() asm volatile("s_waitcnt vmcnt(4)" ::: "memory")
#define VMCNT0() asm volatile("s_waitcnt vmcnt(0)" ::: "memory")
#define BARR() do { asm volatile("" ::: "memory"); __builtin_amdgcn_s_barrier(); asm volatile("" ::: "memory"); } while (0)

__device__ __forceinline__ u16 f2bf(float f) {
  uint32_t u = __builtin_bit_cast(uint32_t, f);
  u += 0x7fffu + ((u >> 16) & 1u);   // RNE
  return (u16)(u >> 16);
}
__device__ __forceinline__ float bf2f(u16 h) {
  uint32_t u = ((uint32_t)h) << 16;
  return __builtin_bit_cast(float, u);
}

// ---------------- merged prep: router (+X->bf16) AND all 3 weight transposes ----------------
// blocks [0,1024): router, 4 tokens/block.
// blocks [1024,1024+12288): transpose tiles; z = tile/512 selects tensor+expert.
__global__ __launch_bounds__(256)
void prep_kernel(const float* __restrict__ X, const float* __restrict__ Wr,
                 int* __restrict__ tok_idx, float* __restrict__ wpair,
                 u16* __restrict__ Xbf,
                 const float* __restrict__ Gf, const float* __restrict__ Uf,
                 const float* __restrict__ Of, u16* __restrict__ tG,
                 u16* __restrict__ tU, u16* __restrict__ tO) {
  __shared__ float tile[64][65];   // transpose staging, +1 pad
  int bid = blockIdx.x;
  if (bid < TT / 4) {
    // ---- router ----
    int wave = threadIdx.x >> 6;
    int lane = threadIdx.x & 63;
    int t = bid * 4 + wave;
    const float4* x4 = (const float4*)(X + (size_t)t * DD);
    float acc[EE];
#pragma unroll
    for (int e = 0; e < EE; e++) acc[e] = 0.f;
#pragma unroll
    for (int i = 0; i < 4; i++) {
      float4 xv = x4[i * 64 + lane];
      ushort4 o;
      o.x = f2bf(xv.x); o.y = f2bf(xv.y); o.z = f2bf(xv.z); o.w = f2bf(xv.w);
      *(ushort4*)&Xbf[(size_t)t * DD + (size_t)(i * 64 + lane) * 4] = o;
      const float4* wr4 = (const float4*)(Wr + (size_t)(i * 256 + lane * 4) * EE);
      float xs[4] = {xv.x, xv.y, xv.z, xv.w};
#pragma unroll
      for (int c = 0; c < 4; c++) {
        float4 wa = wr4[c * 2 + 0];
        float4 wb = wr4[c * 2 + 1];
        acc[0] += xs[c] * wa.x; acc[1] += xs[c] * wa.y;
        acc[2] += xs[c] * wa.z; acc[3] += xs[c] * wa.w;
        acc[4] += xs[c] * wb.x; acc[5] += xs[c] * wb.y;
        acc[6] += xs[c] * wb.z; acc[7] += xs[c] * wb.w;
      }
    }
#pragma unroll
    for (int off = 32; off > 0; off >>= 1)
#pragma unroll
      for (int e = 0; e < EE; e++) acc[e] += __shfl_xor(acc[e], off);
    if (lane == 0) {
      float mx = acc[0];
#pragma unroll
      for (int e = 1; e < EE; e++) mx = fmaxf(mx, acc[e]);
      float p[EE], s = 0.f;
#pragma unroll
      for (int e = 0; e < EE; e++) { p[e] = __expf(acc[e] - mx); s += p[e]; }
      float inv = 1.f / s;
#pragma unroll
      for (int e = 0; e < EE; e++) p[e] *= inv;
      int i0 = 0;
#pragma unroll
      for (int e = 1; e < EE; e++) if (p[e] > p[i0]) i0 = e;
      int i1 = (i0 == 0) ? 1 : 0;
#pragma unroll
      for (int e = 0; e < EE; e++) if (e != i0 && p[e] > p[i1]) i1 = e;
      float denom = p[i0] + p[i1] + 1e-8f;
      tok_idx[t * 2 + 0] = i0;
      tok_idx[t * 2 + 1] = i1;
      wpair[t * 2 + 0] = p[i0] / denom;
      wpair[t * 2 + 1] = p[i1] / denom;
    }
    return;
  }
  // ---- transpose: in [E][R][C] f32 -> out [E][C][R] bf16 ----
  int idx = bid - TT / 4;          // 0..12287
  int z = idx >> 9;                // 0..23
  int tidx = idx & 511;
  const float* in; u16* out; int R, C, shift, e;
  if (z < 8)       { in = Gf; out = tG; R = DD; C = MM; e = z;      shift = 5; }
  else if (z < 16) { in = Uf; out = tU; R = DD; C = MM; e = z - 8;  shift = 5; }
  else             { in = Of; out = tO; R = MM; C = DD; e = z - 16; shift = 4; }
  int cx = tidx & ((1 << shift) - 1);
  int cy = tidx >> shift;
  const float* I = in + (size_t)e * R * C;
  u16* O = out + (size_t)e * R * C;
  int c0 = cx * 64, r0 = cy * 64;
  int t = threadIdx.x;
  {
    int cq = t & 15;          // col quad
    int rb = t >> 4;          // row base
#pragma unroll
    for (int i = 0; i < 4; i++) {
      int r = rb + i * 16;
      float4 v = *(const float4*)&I[(size_t)(r0 + r) * C + c0 + cq * 4];
      tile[cq * 4 + 0][r] = v.x;
      tile[cq * 4 + 1][r] = v.y;
      tile[cq * 4 + 2][r] = v.z;
      tile[cq * 4 + 3][r] = v.w;
    }
  }
  __syncthreads();
  {
    int rseg = (t & 7) * 8;
    int cc = t >> 3;          // 0..31
#pragma unroll
    for (int i = 0; i < 2; i++) {
      int c = cc + i * 32;
      u16x8 o;
#pragma unroll
      for (int k = 0; k < 8; k++) o[k] = f2bf(tile[c][rseg + k]);
      *(u16x8*)&O[(size_t)(c0 + c) * R + r0 + rseg] = o;
    }
  }
}

// ---------------- bucketing: wave-aggregated ballots ----------------
__global__ void bucket_kernel(const int* __restrict__ tok_idx, int* __restrict__ offsets,
                              int* __restrict__ bucket) {
  __shared__ int lcnt[EE];
  __shared__ int lcur[EE];
  int tid = threadIdx.x;   // 1024 threads
  int lane = tid & 63;
  if (tid < EE) lcnt[tid] = 0;
  __syncthreads();
  {
    int cnt[EE];
#pragma unroll
    for (int k = 0; k < EE; k++) cnt[k] = 0;
    for (int i = tid; i < NPAIR; i += 1024) {
      int e = tok_idx[i];
#pragma unroll
      for (int k = 0; k < EE; k++) {
        unsigned long long m = __ballot(e == k);
        cnt[k] += __popcll(m);
      }
    }
    if (lane == 0) {
#pragma unroll
      for (int k = 0; k < EE; k++)
        if (cnt[k]) atomicAdd(&lcnt[k], cnt[k]);
    }
  }
  __syncthreads();
  if (tid == 0) {
    int s = 0;
    for (int e = 0; e < EE; e++) {
      offsets[e] = s;
      lcur[e] = s;
      s += lcnt[e];
    }
    offsets[EE] = s;
  }
  __syncthreads();
  for (int i = tid; i < NPAIR; i += 1024) {
    int e = tok_idx[i];
    int pos = 0;
#pragma unroll
    for (int k = 0; k < EE; k++) {
      unsigned long long m = __ballot(e == k);
      int c = __popcll(m);
      if (c) {
        int leader = (int)__ffsll((long long)m) - 1;
        int base = 0;
        if (lane == leader) base = atomicAdd(&lcur[k], c);
        base = __shfl(base, leader);
        if (e == k) pos = base + __popcll(m & ((1ull << lane) - 1ull));
      }
    }
    bucket[pos] = i;
  }
}

// Map row-tile index rt -> (expert, row0, rows). Tiles never cross expert boundaries.
__device__ __forceinline__ bool tile_map(const int* __restrict__ offsets, int x,
                                         int& expert, int& row0, int& rows) {
  expert = -1;
#pragma unroll 1
  for (int e = 0; e < EE; e++) {
    int o0 = offsets[e], o1 = offsets[e + 1];
    int nt = (o1 - o0 + 127) >> 7;
    if (x < nt) { expert = e; row0 = o0 + (x << 7); rows = min(128, o1 - row0); return true; }
    x -= nt;
  }
  return false;
}

// XCD-aware decode, n0-OUTER / rt-INNER (verified R3: FETCH 119->89MB):
// concurrent blocks on an XCD share the same 1-2 B panels while its 9 A-strips
// stay L2-resident -> WS < 4MB XCD L2.
__device__ __forceinline__ void grid_decode(int bid, int& rt, int& n0) {
  int xcd = bid & 7, slot = bid >> 3;
  rt = xcd * 9 + slot % 9;
  n0 = (slot / 9) * 128;
}

// LDS bank-conflict swizzle (verified: conflicts 0):
// chunk q of row r stored at position q ^ ((r>>1)&3); staging lane permutes SOURCE chunk.

// ---------------- fused gate+up GEMM ----------------
// H = silu(X*Wg + b_gate) * (X*Wu + b_up)  -> Hws (bf16)
// Triple-buffered LDS, prefetch distance 2, counted vmcnt, ONE raw barrier/K-step:
//   { vmcnt(6); barrier; stage(t+2); ds_read x12; MFMA x32 }
__global__ __launch_bounds__(256, 2)
void moe_gemm_gu(const u16* __restrict__ Xbf, const u16* __restrict__ WtG,
                 const u16* __restrict__ WtU, const float* __restrict__ bgate,
                 const float* __restrict__ bup, u16* __restrict__ Hws,
                 const int* __restrict__ offsets, const int* __restrict__ bucket) {
  int rt, n0;
  grid_decode(blockIdx.x, rt, n0);
  int expert, row0, rows;
  if (!tile_map(offsets, rt, expert, row0, rows)) return;

  __shared__ u16 Alds[3 * 128 * 32];
  __shared__ u16 Glds[3 * 128 * 32];
  __shared__ u16 Ulds[3 * 128 * 32];

  int tid = threadIdx.x;
  int wave = tid >> 6, lane = tid & 63;
  int wm = wave >> 1, wn = wave & 1;
  int quad = lane >> 4, l15 = lane & 15;
  int swz = ((lane & 3) ^ ((lane >> 3) & 3)) * 8;   // global source chunk
  int rp  = (quad ^ ((l15 >> 1) & 3)) * 8;          // LDS read chunk position

  long arow0, arow1;
  {
    int r0l = wave * 32 + (lane >> 2);
    int rr0 = min(r0l, rows - 1);
    int rr1 = min(r0l + 16, rows - 1);
    arow0 = (long)(bucket[row0 + rr0] >> 1) * DD;
    arow1 = (long)(bucket[row0 + rr1] >> 1) * DD;
  }
  const u16* A0 = Xbf + arow0 + swz;
  const u16* A1 = Xbf + arow1 + swz;
  size_t bo = (size_t)expert * MM * DD + (size_t)n0 * DD
            + (long)(wave * 32 + (lane >> 2)) * DD + swz;
  const u16* G0 = WtG + bo; const u16* G1 = G0 + 16 * DD;
  const u16* U0 = WtU + bo; const u16* U1 = U0 + 16 * DD;

  int sb0 = (wave * 32) * 32, sb1 = (wave * 32 + 16) * 32;

  f32x4 accG[4][4], accU[4][4];
#pragma unroll
  for (int i = 0; i < 4; i++)
#pragma unroll
    for (int j = 0; j < 4; j++) { accG[i][j] = (f32x4){0,0,0,0}; accU[i][j] = (f32x4){0,0,0,0}; }

  auto stage = [&](int b) {
    int bo2 = b * (128 * 32);
    async16(&Alds[bo2 + sb0], A0); async16(&Alds[bo2 + sb1], A1);
    async16(&Glds[bo2 + sb0], G0); async16(&Glds[bo2 + sb1], G1);
    async16(&Ulds[bo2 + sb0], U0); async16(&Ulds[bo2 + sb1], U1);
    A0 += 32; A1 += 32; G0 += 32; G1 += 32; U0 += 32; U1 += 32;
  };

  auto compute = [&](int b) {
    int ro = b * (128 * 32);
    // preload ALL 12 fragments, then one long 32-MFMA burst
    bf16x8 af[4], bg[4], bu[4];
#pragma unroll
    for (int i = 0; i < 4; i++) {
      af[i] = *(const bf16x8*)&Alds[ro + (wm * 64 + i * 16 + l15) * 32 + rp];
      bg[i] = *(const bf16x8*)&Glds[ro + (wn * 64 + i * 16 + l15) * 32 + rp];
      bu[i] = *(const bf16x8*)&Ulds[ro + (wn * 64 + i * 16 + l15) * 32 + rp];
    }
    __builtin_amdgcn_s_setprio(1);
#pragma unroll
    for (int i = 0; i < 4; i++)
#pragma unroll
      for (int j = 0; j < 4; j++)
        accG[i][j] = __builtin_amdgcn_mfma_f32_16x16x32_bf16(af[i], bg[j], accG[i][j], 0, 0, 0);
#pragma unroll
    for (int i = 0; i < 4; i++)
#pragma unroll
      for (int j = 0; j < 4; j++)
        accU[i][j] = __builtin_amdgcn_mfma_f32_16x16x32_bf16(af[i], bu[j], accU[i][j], 0, 0, 0);
    __builtin_amdgcn_s_setprio(0);
  };

  constexpr int NT = DD / 32;   // 32
  stage(0);
  stage(1);
  int br = 0, bs = 2;
#pragma unroll 3
  for (int t = 0; t < NT - 2; ++t) {   // 30 iters = 3 x 10, buffer idx compile-time per copy
    VMCNT6();
    BARR();
    stage(bs);
    compute(br);
    bs = br; br = (br + 1 == 3) ? 0 : br + 1;
  }
  VMCNT6(); BARR(); compute(br); br = (br + 1 == 3) ? 0 : br + 1;
  VMCNT0(); BARR(); compute(br);

  // epilogue: Hws = silu(g + bg) * (u + bu); C/D layout col = lane&15, row = quad*4 + r
#pragma unroll
  for (int i = 0; i < 4; i++) {
    int lrb = wm * 64 + i * 16 + quad * 4;
#pragma unroll
    for (int j = 0; j < 4; j++) {
      int gc = n0 + wn * 64 + j * 16 + l15;
      float bgv = bgate[expert * MM + gc];
      float buv = bup[expert * MM + gc];
#pragma unroll
      for (int r = 0; r < 4; r++) {
        int lr = lrb + r;
        if (lr < rows) {
          int grow = row0 + lr;
          float g = accG[i][j][r] + bgv;
          float u = accU[i][j][r] + buv;
          float sg = g / (1.f + __expf(-g));
          Hws[(size_t)grow * MM + gc] = f2bf(sg * u);
        }
      }
    }
  }
}

// ---------------- output GEMM: Ypart[pair] = w*(H*Wo + b_out) ----------------
__global__ __launch_bounds__(256, 3)
void moe_gemm_out(const u16* __restrict__ Hmat, const u16* __restrict__ WtO,
                  const float* __restrict__ bias, float* __restrict__ Ypart,
                  const int* __restrict__ offsets, const int* __restrict__ bucket,
                  const float* __restrict__ wpair) {
  int rt, n0;
  grid_decode(blockIdx.x, rt, n0);
  int expert, row0, rows;
  if (!tile_map(offsets, rt, expert, row0, rows)) return;

  __shared__ u16 Alds[3 * 128 * 32];
  __shared__ u16 Blds[3 * 128 * 32];

  int tid = threadIdx.x;
  int wave = tid >> 6, lane = tid & 63;
  int wm = wave >> 1, wn = wave & 1;
  int quad = lane >> 4, l15 = lane & 15;
  int swz = ((lane & 3) ^ ((lane >> 3) & 3)) * 8;
  int rp  = (quad ^ ((l15 >> 1) & 3)) * 8;

  long arow0, arow1;
  {
    int r0l = wave * 32 + (lane >> 2);
    int rr0 = min(r0l, rows - 1);
    int rr1 = min(r0l + 16, rows - 1);
    arow0 = (long)(row0 + rr0) * MM;   // Hws already in bucket-row order
    arow1 = (long)(row0 + rr1) * MM;
  }
  const u16* A0 = Hmat + arow0 + swz;
  const u16* A1 = Hmat + arow1 + swz;
  const u16* B0 = WtO + (size_t)expert * DD * MM + (size_t)n0 * MM
                + (long)(wave * 32 + (lane >> 2)) * MM + swz;
  const u16* B1 = B0 + 16 * MM;

  int sb0 = (wave * 32) * 32, sb1 = (wave * 32 + 16) * 32;

  f32x4 acc[4][4];
#pragma unroll
  for (int i = 0; i < 4; i++)
#pragma unroll
    for (int j = 0; j < 4; j++) acc[i][j] = (f32x4){0, 0, 0, 0};

  auto stage = [&](int b) {
    int bo2 = b * (128 * 32);
    async16(&Alds[bo2 + sb0], A0); async16(&Alds[bo2 + sb1], A1);
    async16(&Blds[bo2 + sb0], B0); async16(&Blds[bo2 + sb1], B1);
    A0 += 32; A1 += 32; B0 += 32; B1 += 32;
  };

  auto compute = [&](int b) {
    int ro = b * (128 * 32);
    bf16x8 af[4], bf[4];
#pragma unroll
    for (int i = 0; i < 4; i++) {
      af[i] = *(const bf16x8*)&Alds[ro + (wm * 64 + i * 16 + l15) * 32 + rp];
      bf[i] = *(const bf16x8*)&Blds[ro + (wn * 64 + i * 16 + l15) * 32 + rp];
    }
    __builtin_amdgcn_s_setprio(1);
#pragma unroll
    for (int i = 0; i < 4; i++)
#pragma unroll
      for (int j = 0; j < 4; j++)
        acc[i][j] = __builtin_amdgcn_mfma_f32_16x16x32_bf16(af[i], bf[j], acc[i][j], 0, 0, 0);
    __builtin_amdgcn_s_setprio(0);
  };

  constexpr int NT = MM / 32;   // 64
  stage(0);
  stage(1);
  int br = 0, bs = 2;
#pragma unroll 2
  for (int t = 0; t < NT - 2; ++t) {   // 62 iters
    VMCNT4();
    BARR();
    stage(bs);
    compute(br);
    bs = br; br = (br + 1 == 3) ? 0 : br + 1;
  }
  VMCNT4(); BARR(); compute(br); br = (br + 1 == 3) ? 0 : br + 1;
  VMCNT0(); BARR(); compute(br);

  // epilogue
#pragma unroll
  for (int i = 0; i < 4; i++) {
    int lrb = wm * 64 + i * 16 + quad * 4;
#pragma unroll
    for (int j = 0; j < 4; j++) {
      int gc = n0 + wn * 64 + j * 16 + l15;
      float bv = bias[expert * DD + gc];
#pragma unroll
      for (int r = 0; r < 4; r++) {
        int lr = lrb + r;
        if (lr < rows) {
          int grow = row0 + lr;
          int p = bucket[grow];
          float w = wpair[p];
          Ypart[(size_t)p * DD + gc] = w * (acc[i][j][r] + bv);
        }
      }
    }
  }
}

// ---------------- combine the two expert contributions per token ----------------
__global__ void combine_kernel(const float* __restrict__ Ypart, float* __restrict__ out) {
  int i = blockIdx.x * 256 + threadIdx.x;   // over TT*DD/4
  int t = i >> 8;          // DD/4 = 256 float4 per token
  int c4 = i & 255;
  const float4* y0 = (const float4*)(Ypart + (size_t)(2 * t) * DD) + c4;
  const float4* y1 = (const float4*)(Ypart + (size_t)(2 * t + 1) * DD) + c4;
  float4 a = *y0, b = *y1;
  float4 o;
  o.x = a.x + b.x; o.y = a.y + b.y; o.z = a.z + b.z; o.w = a.w + b.w;
  ((float4*)out)[i] = o;
}

extern "C" void kernel_launch(void* const* d_in, const int* in_sizes, int n_in,
                              void* d_out, int out_size, void* d_ws, size_t ws_size,
                              hipStream_t stream) {
  const float* residual = (const float*)d_in[0];
  const float* W_router = (const float*)d_in[1];
  const float* W_gate   = (const float*)d_in[2];
  const float* b_gate   = (const float*)d_in[3];
  const float* W_up     = (const float*)d_in[4];
  const float* b_up     = (const float*)d_in[5];
  const float* W_out    = (const float*)d_in[6];
  const float* b_out    = (const float*)d_in[7];
  float* out = (float*)d_out;

  char* ws = (char*)d_ws;
  int*   tok_idx = (int*)(ws + 0);                       // 8192 ints
  float* wpair   = (float*)(ws + 32768);                 // 8192 floats
  int*   offsets = (int*)(ws + 65536);                   // 9 ints
  int*   bucket  = (int*)(ws + 65536 + 512);             // 8192 ints
  u16*   Xbf  = (u16*)(ws + 131072);                                     // 8 MB
  u16*   WtG  = Xbf + (size_t)TT * DD;                                   // 32 MB  [E][M][D]
  u16*   WtU  = WtG + (size_t)EE * MM * DD;                              // 32 MB  [E][M][D]
  u16*   WtO  = WtU + (size_t)EE * MM * DD;                              // 32 MB  [E][D][M]
  u16*   Hws  = WtO + (size_t)EE * DD * MM;                              // 32 MB  [8192][M]
  float* Ypart = (float*)(Hws + (size_t)NPAIR * MM);                     // 32 MB  [8192][D]

  // router + X->bf16 + all weight transposes, one launch
  prep_kernel<<<dim3(TT / 4 + 24 * 512), dim3(256), 0, stream>>>(
      residual, W_router, tok_idx, wpair, Xbf, W_gate, W_up, W_out, WtG, WtU, WtO);
  bucket_kernel<<<dim3(1), dim3(1024), 0, stream>>>(tok_idx, offsets, bucket);
  // fused gate+up GEMM, then output GEMM
  moe_gemm_gu<<<dim3(8 * 9 * 16), dim3(256), 0, stream>>>(Xbf, WtG, WtU, b_gate, b_up, Hws, offsets, bucket);
  moe_gemm_out<<<dim3(8 * 9 * 8), dim3(256), 0, stream>>>(Hws, WtO, b_out, Ypart, offsets, bucket, wpair);
  // combine
  combine_kernel<<<dim3(TT * DD / 4 / 256), dim3(256), 0, stream>>>(Ypart, out);
}